// Round 11
// baseline (111.887 us; speedup 1.0000x reference)
//
#include <hip/hip_runtime.h>

// Problem constants
#define HWSZ 65536             // 256*256
#define PLANE (3 * HWSZ)       // one batch's [3,H,W]
#define OUTSTRIDE (8 * PLANE)  // one full output tensor [8,3,256,256]
#define MAGIC 0x13572468       // != 0xAAAAAAAA ws poison

// ---------------------------------------------------------------------------
// Fused MLP, 48 blocks x 256, R3-style output-split layers chained by
// producer-consumer flags (R10-proven pattern; NOT an all-to-all barrier).
//   stage1: blocks 0..47: h[k, :, ob:ob+16]            (k=blk/12, ob=16*(blk%12))
//   stage2: blocks 0..47: outs[k, :, ob:ob+16]          (waits 12 flags of k)
//   stage3: blocks 0..23: hc[:, ob2:ob2+8]              (waits all 48)
//   stage4: blocks 0..23: param[:, ob2:ob2+8]           (waits all 24)
__global__ __launch_bounds__(256) void k_mlp(
    const float* __restrict__ f, const float* __restrict__ bf,
    const float* __restrict__ pw1, const float* __restrict__ pb1,
    const float* __restrict__ pw2, const float* __restrict__ pb2,
    const float* __restrict__ fw1, const float* __restrict__ fb1,
    const float* __restrict__ fw2, const float* __restrict__ fb2,
    float* __restrict__ ws) {
  __shared__ float smem[6656];
  int t = threadIdx.x, blk = blockIdx.x;

  float* h     = ws;          // [4,8,192]
  float* outs  = ws + 6144;   // [4,8,192]
  float* hc    = ws + 12288;  // [8,192]
  float* param = ws + 13824;  // [8,192]
  int* flags1 = (int*)(ws + 16384);   // 48, stride 16 dwords
  int* flags2 = flags1 + 48 * 16;     // 48
  int* flags3 = flags2 + 48 * 16;     // 24

  int k = blk / 12, ot = blk - k * 12, ob = ot * 16;

  // ---- stage 1: h[k,b,ob..ob+16] = relu(feat @ W1[k] + b1) ----
  {
    int o = t & 15, s = t >> 4;  // 16 k-splits of 32
    float* sf  = smem;           // 8*512
    float* red = smem + 4096;    // 16*128
    const float* feat = (k & 1) ? bf : f;
    for (int i = t; i < 4096; i += 256) sf[i] = feat[i];
    const float* w = pw1 + (size_t)k * (512 * 192) + ob + o;
    float wr[32];
#pragma unroll
    for (int j = 0; j < 32; ++j) wr[j] = w[(size_t)(s + 16 * j) * 192];
    __syncthreads();
    float acc[8];
#pragma unroll
    for (int b = 0; b < 8; ++b) {
      float a = 0.f;
      const float* sfb = sf + b * 512 + s;
#pragma unroll
      for (int j = 0; j < 32; ++j) a = fmaf(wr[j], sfb[16 * j], a);
      acc[b] = a;
    }
#pragma unroll
    for (int b = 0; b < 8; ++b) red[s * 128 + b * 16 + o] = acc[b];
    __syncthreads();
    if (t < 128) {
      float a = 0.f;
#pragma unroll
      for (int s2 = 0; s2 < 16; ++s2) a += red[s2 * 128 + t];
      int b = t >> 4, oo = t & 15;
      a += pb1[k * 192 + ob + oo];
      h[(k * 8 + b) * 192 + ob + oo] = fmaxf(a, 0.f);
    }
    __syncthreads();  // drain stores before fence
    if (t == 0) {
      __threadfence();
      atomicExch(&flags1[blk * 16], MAGIC);
    }
  }

  // ---- stage 2: outs[k,b,ob..ob+16] = h[k] @ W2[k] + b2 ----
  if (t < 12) {
    while (atomicAdd(&flags1[(k * 12 + t) * 16], 0) != MAGIC)
      __builtin_amdgcn_s_sleep(2);
  }
  __syncthreads();
  if (t == 0) __threadfence();  // acquire
  __syncthreads();
  {
    int o = t & 15, s = t >> 4;  // 16 k-splits of 12
    float* sh  = smem;           // 8*192
    float* red = smem + 2048;    // 16*128
    for (int i = t; i < 1536; i += 256) sh[i] = h[k * 1536 + i];
    const float* w = pw2 + (size_t)k * (192 * 192) + ob + o;
    float wr[12];
#pragma unroll
    for (int j = 0; j < 12; ++j) wr[j] = w[(size_t)(s + 16 * j) * 192];
    __syncthreads();
    float acc[8];
#pragma unroll
    for (int b = 0; b < 8; ++b) {
      float a = 0.f;
      const float* shb = sh + b * 192 + s;
#pragma unroll
      for (int j = 0; j < 12; ++j) a = fmaf(wr[j], shb[16 * j], a);
      acc[b] = a;
    }
#pragma unroll
    for (int b = 0; b < 8; ++b) red[s * 128 + b * 16 + o] = acc[b];
    __syncthreads();
    if (t < 128) {
      float a = 0.f;
#pragma unroll
      for (int s2 = 0; s2 < 16; ++s2) a += red[s2 * 128 + t];
      int b = t >> 4, oo = t & 15;
      outs[(k * 8 + b) * 192 + ob + oo] = a + pb2[k * 192 + ob + oo];
    }
    __syncthreads();
    if (t == 0) {
      __threadfence();
      atomicExch(&flags2[blk * 16], MAGIC);
    }
  }

  if (blk >= 24) return;

  // ---- stage 3: hc[:, ob2..ob2+8] = relu(cat @ fW1 + fb1) ----
  if (t < 48) {
    while (atomicAdd(&flags2[t * 16], 0) != MAGIC)
      __builtin_amdgcn_s_sleep(2);
  }
  __syncthreads();
  if (t == 0) __threadfence();  // acquire
  __syncthreads();
  int ob2 = blk * 8;
  {
    int o = t & 7, s = t >> 3;  // 32 k-splits of 18
    float* sc  = smem;          // 8*576
    float* red = smem + 4608;   // 32*64
    for (int idx = t; idx < 4608; idx += 256) {
      int b = idx / 576, i = idx - b * 576;
      float v;
      if (i < 192)      v = outs[(0 * 8 + b) * 192 + i];
      else if (i < 384) v = outs[(1 * 8 + b) * 192 + (i - 192)];
      else              v = outs[(2 * 8 + b) * 192 + (i - 384)] +
                            outs[(3 * 8 + b) * 192 + (i - 384)];
      sc[idx] = v;
    }
    const float* w = fw1 + ob2 + o;
    float wr[18];
#pragma unroll
    for (int j = 0; j < 18; ++j) wr[j] = w[(size_t)(s + 32 * j) * 192];
    __syncthreads();
    float acc[8];
#pragma unroll
    for (int b = 0; b < 8; ++b) {
      float a = 0.f;
      const float* scb = sc + b * 576 + s;
#pragma unroll
      for (int j = 0; j < 18; ++j) a = fmaf(wr[j], scb[32 * j], a);
      acc[b] = a;
    }
#pragma unroll
    for (int b = 0; b < 8; ++b) red[s * 64 + b * 8 + o] = acc[b];
    __syncthreads();
    if (t < 64) {
      float a = 0.f;
#pragma unroll
      for (int s2 = 0; s2 < 32; ++s2) a += red[s2 * 64 + t];
      int b = t >> 3, oo = t & 7;
      a += fb1[ob2 + oo];
      hc[b * 192 + ob2 + oo] = fmaxf(a, 0.f);
    }
    __syncthreads();
    if (t == 0) {
      __threadfence();
      atomicExch(&flags3[blk * 16], MAGIC);
    }
  }

  // ---- stage 4: param[:, ob2..ob2+8] = hc @ fW2 + fb2 ----
  if (t < 24) {
    while (atomicAdd(&flags3[t * 16], 0) != MAGIC)
      __builtin_amdgcn_s_sleep(2);
  }
  __syncthreads();
  if (t == 0) __threadfence();  // acquire
  __syncthreads();
  {
    int o = t & 7, s = t >> 3;  // 32 k-splits of 6
    float* sh  = smem;          // 8*192
    float* red = smem + 2048;   // 32*64
    for (int i = t; i < 1536; i += 256) sh[i] = hc[i];
    const float* w = fw2 + ob2 + o;
    float wr[6];
#pragma unroll
    for (int j = 0; j < 6; ++j) wr[j] = w[(size_t)(s + 32 * j) * 192];
    __syncthreads();
    float acc[8];
#pragma unroll
    for (int b = 0; b < 8; ++b) {
      float a = 0.f;
      const float* shb = sh + b * 192 + s;
#pragma unroll
      for (int j = 0; j < 6; ++j) a = fmaf(wr[j], shb[32 * j], a);
      acc[b] = a;
    }
#pragma unroll
    for (int b = 0; b < 8; ++b) red[s * 64 + b * 8 + o] = acc[b];
    __syncthreads();
    if (t < 64) {
      float a = 0.f;
#pragma unroll
      for (int s2 = 0; s2 < 32; ++s2) a += red[s2 * 64 + t];
      int b = t >> 3, oo = t & 7;
      param[b * 192 + ob2 + oo] = a + fb2[ob2 + oo];
    }
  }
}

// ---------------------------------------------------------------------------
// Render. LUT entry e[k] = {S_k*norm/64, p_k*norm}; eval = one b64 LDS gather
// + one FMA. LUT built with a per-wave prefix scan (width-64 shfl_up).
__global__ __launch_bounds__(256) void k_render(
    const float* __restrict__ x, const float* __restrict__ ws,
    float* __restrict__ out) {
  int b = blockIdx.y, t = threadIdx.x;
  int wave = t >> 6, lane = t & 63;
  const float* outs  = ws + 6144;
  const float* param = ws + 13824;
  __shared__ float2 tab[576];

  for (int cur = wave; cur < 9; cur += 4) {
    int oi = cur / 3, c = cur - oi * 3;
    const float* src = (oi == 0) ? param + b * 192 + c * 64
                                 : outs + ((oi - 1) * 8 + b) * 192 + c * 64;
    float p = src[lane];
    float v = p;  // inclusive scan
#pragma unroll
    for (int d = 1; d < 64; d <<= 1) {
      float n = __shfl_up(v, d, 64);
      if (lane >= d) v += n;
    }
    float total = __shfl(v, 63, 64);
    float norm = 64.f / (total + 1e-30f);
    tab[cur * 64 + lane] = make_float2((v - p) * 0.015625f * norm, p * norm);
  }
  __syncthreads();

  auto ev = [&](int cur, float v) -> float {
    int k = (int)(v * 64.f);
    k = k < 0 ? 0 : (k > 63 ? 63 : k);
    float2 e = tab[cur * 64 + k];
    float tt = v - (float)k * 0.015625f;
    return fmaf(tt, e.y, e.x);
  };
  auto ev4 = [&](int cur, float4 v) -> float4 {
    float4 r;
    r.x = ev(cur, v.x); r.y = ev(cur, v.y);
    r.z = ev(cur, v.z); r.w = ev(cur, v.w);
    return r;
  };

  int s4 = blockIdx.x * 256 + t;
  const float* xb = x + (size_t)b * PLANE;
  float4 vr = ((const float4*)(xb))[s4];
  float4 vg = ((const float4*)(xb + HWSZ))[s4];
  float4 vb = ((const float4*)(xb + 2 * HWSZ))[s4];

  float4 gr;
  gr.x = fmaf(0.299f, vr.x, fmaf(0.587f, vg.x, 0.114f * vb.x));
  gr.y = fmaf(0.299f, vr.y, fmaf(0.587f, vg.y, 0.114f * vb.y));
  gr.z = fmaf(0.299f, vr.z, fmaf(0.587f, vg.z, 0.114f * vb.z));
  gr.w = fmaf(0.299f, vr.w, fmaf(0.587f, vg.w, 0.114f * vb.w));

  float* o0 = out + (size_t)b * PLANE;
  float* o1 = out + OUTSTRIDE + (size_t)b * PLANE;
  float* o2 = out + 2 * OUTSTRIDE + (size_t)b * PLANE;

  ((float4*)(o0))[s4]            = ev4(0, vr);
  ((float4*)(o0 + HWSZ))[s4]     = ev4(1, vg);
  ((float4*)(o0 + 2 * HWSZ))[s4] = ev4(2, vb);
  ((float4*)(o1))[s4]            = ev4(3, gr);
  ((float4*)(o1 + HWSZ))[s4]     = ev4(4, gr);
  ((float4*)(o1 + 2 * HWSZ))[s4] = ev4(5, gr);
  ((float4*)(o2))[s4]            = ev4(6, gr);
  ((float4*)(o2 + HWSZ))[s4]     = ev4(7, gr);
  ((float4*)(o2 + 2 * HWSZ))[s4] = ev4(8, gr);
}

// ---------------------------------------------------------------------------
extern "C" void kernel_launch(void* const* d_in, const int* in_sizes, int n_in,
                              void* d_out, int out_size, void* d_ws, size_t ws_size,
                              hipStream_t stream) {
  const float* x   = (const float*)d_in[0];
  const float* f   = (const float*)d_in[1];
  const float* bf  = (const float*)d_in[2];
  const float* pw1 = (const float*)d_in[3];
  const float* pb1 = (const float*)d_in[4];
  const float* pw2 = (const float*)d_in[5];
  const float* pb2 = (const float*)d_in[6];
  const float* fw1 = (const float*)d_in[7];
  const float* fb1 = (const float*)d_in[8];
  const float* fw2 = (const float*)d_in[9];
  const float* fb2 = (const float*)d_in[10];
  float* out = (float*)d_out;
  float* ws  = (float*)d_ws;

  k_mlp<<<48, 256, 0, stream>>>(f, bf, pw1, pb1, pw2, pb2, fw1, fb1, fw2,
                                fb2, ws);
  dim3 grid(64, 8);
  k_render<<<grid, 256, 0, stream>>>(x, ws, out);
}

// Round 12
// 100.082 us; speedup vs baseline: 1.1179x; 1.1179x over previous
//
#include <hip/hip_runtime.h>

// Problem constants
#define HWSZ 65536             // 256*256
#define PLANE (3 * HWSZ)       // one batch's [3,H,W]
#define OUTSTRIDE (8 * PLANE)  // one full output tensor [8,3,256,256]
#define MAGIC 0x13572468       // != 0xAAAAAAAA ws poison

// ---------------------------------------------------------------------------
// Fused MLP: 32 blocks x 384.
//  Phase A (all 32): proj for (k=blk>>3, b=blk&7) -> outs, flagA[k*8+b]
//  Phase B1 (all 32): fcat fc1 for (b=blk&7, quarter c4=blk>>3): waits 4
//    flagA of b, computes hc[b, c4*48 .. +48] -> flagB[blk]
//  Phase B2 (all 32): waits 4 flagB of b, computes param[b, c4*48 .. +48]
// Shallow (1-level), narrow (4-flag) handshakes only — R10/R11 lesson.
__global__ __launch_bounds__(384) void k_mlp(
    const float* __restrict__ f, const float* __restrict__ bf,
    const float* __restrict__ pw1, const float* __restrict__ pb1,
    const float* __restrict__ pw2, const float* __restrict__ pb2,
    const float* __restrict__ fw1, const float* __restrict__ fb1,
    const float* __restrict__ fw2, const float* __restrict__ fb2,
    float* __restrict__ ws) {
  __shared__ float smem[2304];
  int t = threadIdx.x, blk = blockIdx.x;

  float* outs  = ws;          // [4,8,192]
  float* hc    = ws + 12288;  // [8,192]
  float* param = ws + 13824;  // [8,192]
  int* fbase = (int*)(ws + 16384);
  // flagA[i] = fbase[i*16] (i<32); flagB[i] = fbase[(64+i)*16]

  // ======== Phase A: proj for (k,b) ========
  int k = blk >> 3, b = blk & 7;
  {
    int q = t % 48, s = t / 48;  // s in 0..7
    float* sf  = smem;           // 512
    float* red = smem + 512;     // 8*192
    float* sh  = smem + 2048;    // 192

    const float* feat = ((k & 1) ? bf : f) + b * 512;
    for (int i = t; i < 512; i += 384) sf[i] = feat[i];
    __syncthreads();

    {  // 512 -> 192
      const float4* w = (const float4*)(pw1 + (size_t)k * (512 * 192));
      float4 acc = {0.f, 0.f, 0.f, 0.f};
      int i0 = s * 64;
      for (int r = 0; r < 4; ++r) {
        float4 wv[16];
#pragma unroll
        for (int j = 0; j < 16; ++j)
          wv[j] = w[(size_t)(i0 + r * 16 + j) * 48 + q];
#pragma unroll
        for (int j = 0; j < 16; ++j) {
          float v = sf[i0 + r * 16 + j];
          acc.x = fmaf(v, wv[j].x, acc.x); acc.y = fmaf(v, wv[j].y, acc.y);
          acc.z = fmaf(v, wv[j].z, acc.z); acc.w = fmaf(v, wv[j].w, acc.w);
        }
      }
      ((float4*)(red + s * 192))[q] = acc;
    }
    __syncthreads();
    if (t < 192) {
      float a = pb1[k * 192 + t];
#pragma unroll
      for (int s2 = 0; s2 < 8; ++s2) a += red[s2 * 192 + t];
      sh[t] = fmaxf(a, 0.f);
    }
    __syncthreads();
    {  // 192 -> 192
      const float4* w = (const float4*)(pw2 + (size_t)k * (192 * 192));
      float4 acc = {0.f, 0.f, 0.f, 0.f};
      int i0 = s * 24;
      for (int r = 0; r < 2; ++r) {
        float4 wv[12];
#pragma unroll
        for (int j = 0; j < 12; ++j)
          wv[j] = w[(size_t)(i0 + r * 12 + j) * 48 + q];
#pragma unroll
        for (int j = 0; j < 12; ++j) {
          float v = sh[i0 + r * 12 + j];
          acc.x = fmaf(v, wv[j].x, acc.x); acc.y = fmaf(v, wv[j].y, acc.y);
          acc.z = fmaf(v, wv[j].z, acc.z); acc.w = fmaf(v, wv[j].w, acc.w);
        }
      }
      ((float4*)(red + s * 192))[q] = acc;
    }
    __syncthreads();
    if (t < 192) {
      float a = pb2[k * 192 + t];
#pragma unroll
      for (int s2 = 0; s2 < 8; ++s2) a += red[s2 * 192 + t];
      outs[(k * 8 + b) * 192 + t] = a;
    }
    __syncthreads();  // drain stores before fence
    if (t == 0) {
      __threadfence();
      atomicExch(&fbase[blk * 16], MAGIC);
    }
  }

  // ======== Phase B1: fc1 for (b2 = blk&7, quarter c4 = blk>>3) ========
  int b2 = blk & 7, c4 = blk >> 3, ob2 = c4 * 48;
  if (t < 4) {
    while (atomicAdd(&fbase[(t * 8 + b2) * 16], 0) != MAGIC)
      __builtin_amdgcn_s_sleep(2);
  }
  __syncthreads();
  if (t == 0) __threadfence();  // acquire
  __syncthreads();

  {
    int q = t % 12, s = t / 12;  // s in 0..31, 18-deep K slices
    float* sc  = smem;           // 576
    float* red = smem + 576;     // 32*48
    for (int idx = t; idx < 576; idx += 384) {
      float v;
      if (idx < 192)      v = outs[(0 * 8 + b2) * 192 + idx];
      else if (idx < 384) v = outs[(1 * 8 + b2) * 192 + (idx - 192)];
      else                v = outs[(2 * 8 + b2) * 192 + (idx - 384)] +
                              outs[(3 * 8 + b2) * 192 + (idx - 384)];
      sc[idx] = v;
    }
    const float4* w = (const float4*)fw1;
    float4 acc = {0.f, 0.f, 0.f, 0.f};
    int i0 = s * 18;
    {
      float4 wv[18];
#pragma unroll
      for (int j = 0; j < 18; ++j)
        wv[j] = w[(size_t)(i0 + j) * 48 + (ob2 >> 2) + q];
      __syncthreads();  // sc ready
#pragma unroll
      for (int j = 0; j < 18; ++j) {
        float v = sc[i0 + j];
        acc.x = fmaf(v, wv[j].x, acc.x); acc.y = fmaf(v, wv[j].y, acc.y);
        acc.z = fmaf(v, wv[j].z, acc.z); acc.w = fmaf(v, wv[j].w, acc.w);
      }
    }
    ((float4*)(red + s * 48))[q] = acc;
    __syncthreads();
    if (t < 48) {
      float a = fb1[ob2 + t];
#pragma unroll
      for (int s2 = 0; s2 < 32; ++s2) a += red[s2 * 48 + t];
      hc[b2 * 192 + ob2 + t] = fmaxf(a, 0.f);
    }
    __syncthreads();
    if (t == 0) {
      __threadfence();
      atomicExch(&fbase[(64 + blk) * 16], MAGIC);
    }
  }

  // ======== Phase B2: fc2, same (b2, c4) ========
  if (t < 4) {
    while (atomicAdd(&fbase[(64 + t * 8 + b2) * 16], 0) != MAGIC)
      __builtin_amdgcn_s_sleep(2);
  }
  __syncthreads();
  if (t == 0) __threadfence();  // acquire
  __syncthreads();

  {
    int q = t % 12, s = t / 12;  // 6-deep K slices
    float* sh  = smem;           // 192
    float* red = smem + 576;     // 32*48
    if (t < 192) sh[t] = hc[b2 * 192 + t];
    const float4* w = (const float4*)fw2;
    float4 acc = {0.f, 0.f, 0.f, 0.f};
    int i0 = s * 6;
    {
      float4 wv[6];
#pragma unroll
      for (int j = 0; j < 6; ++j)
        wv[j] = w[(size_t)(i0 + j) * 48 + (ob2 >> 2) + q];
      __syncthreads();  // sh ready
#pragma unroll
      for (int j = 0; j < 6; ++j) {
        float v = sh[i0 + j];
        acc.x = fmaf(v, wv[j].x, acc.x); acc.y = fmaf(v, wv[j].y, acc.y);
        acc.z = fmaf(v, wv[j].z, acc.z); acc.w = fmaf(v, wv[j].w, acc.w);
      }
    }
    ((float4*)(red + s * 48))[q] = acc;
    __syncthreads();
    if (t < 48) {
      float a = fb2[ob2 + t];
#pragma unroll
      for (int s2 = 0; s2 < 32; ++s2) a += red[s2 * 48 + t];
      param[b2 * 192 + ob2 + t] = a;
    }
  }
}

// ---------------------------------------------------------------------------
// Render. x float4 loads issued BEFORE the LUT build (overlapped latency).
// LUT entry e[k] = {S_k*norm/64, p_k*norm}; eval = one b64 LDS gather + FMA.
__global__ __launch_bounds__(256) void k_render(
    const float* __restrict__ x, const float* __restrict__ ws,
    float* __restrict__ out) {
  int b = blockIdx.y, t = threadIdx.x;
  int wave = t >> 6, lane = t & 63;
  const float* outs  = ws;
  const float* param = ws + 13824;
  __shared__ float2 tab[576];

  // prefetch x
  int s4 = blockIdx.x * 256 + t;
  const float* xb = x + (size_t)b * PLANE;
  float4 vr = ((const float4*)(xb))[s4];
  float4 vg = ((const float4*)(xb + HWSZ))[s4];
  float4 vb = ((const float4*)(xb + 2 * HWSZ))[s4];

  for (int cur = wave; cur < 9; cur += 4) {
    int oi = cur / 3, c = cur - oi * 3;
    const float* src = (oi == 0) ? param + b * 192 + c * 64
                                 : outs + ((oi - 1) * 8 + b) * 192 + c * 64;
    float p = src[lane];
    float v = p;  // inclusive scan
#pragma unroll
    for (int d = 1; d < 64; d <<= 1) {
      float n = __shfl_up(v, d, 64);
      if (lane >= d) v += n;
    }
    float total = __shfl(v, 63, 64);
    float norm = 64.f / (total + 1e-30f);
    tab[cur * 64 + lane] = make_float2((v - p) * 0.015625f * norm, p * norm);
  }
  __syncthreads();

  auto ev = [&](int cur, float v) -> float {
    int k = (int)(v * 64.f);
    k = k < 0 ? 0 : (k > 63 ? 63 : k);
    float2 e = tab[cur * 64 + k];
    float tt = v - (float)k * 0.015625f;
    return fmaf(tt, e.y, e.x);
  };
  auto ev4 = [&](int cur, float4 v) -> float4 {
    float4 r;
    r.x = ev(cur, v.x); r.y = ev(cur, v.y);
    r.z = ev(cur, v.z); r.w = ev(cur, v.w);
    return r;
  };

  float4 gr;
  gr.x = fmaf(0.299f, vr.x, fmaf(0.587f, vg.x, 0.114f * vb.x));
  gr.y = fmaf(0.299f, vr.y, fmaf(0.587f, vg.y, 0.114f * vb.y));
  gr.z = fmaf(0.299f, vr.z, fmaf(0.587f, vg.z, 0.114f * vb.z));
  gr.w = fmaf(0.299f, vr.w, fmaf(0.587f, vg.w, 0.114f * vb.w));

  float* o0 = out + (size_t)b * PLANE;
  float* o1 = out + OUTSTRIDE + (size_t)b * PLANE;
  float* o2 = out + 2 * OUTSTRIDE + (size_t)b * PLANE;

  ((float4*)(o0))[s4]            = ev4(0, vr);
  ((float4*)(o0 + HWSZ))[s4]     = ev4(1, vg);
  ((float4*)(o0 + 2 * HWSZ))[s4] = ev4(2, vb);
  ((float4*)(o1))[s4]            = ev4(3, gr);
  ((float4*)(o1 + HWSZ))[s4]     = ev4(4, gr);
  ((float4*)(o1 + 2 * HWSZ))[s4] = ev4(5, gr);
  ((float4*)(o2))[s4]            = ev4(6, gr);
  ((float4*)(o2 + HWSZ))[s4]     = ev4(7, gr);
  ((float4*)(o2 + 2 * HWSZ))[s4] = ev4(8, gr);
}

// ---------------------------------------------------------------------------
extern "C" void kernel_launch(void* const* d_in, const int* in_sizes, int n_in,
                              void* d_out, int out_size, void* d_ws, size_t ws_size,
                              hipStream_t stream) {
  const float* x   = (const float*)d_in[0];
  const float* f   = (const float*)d_in[1];
  const float* bf  = (const float*)d_in[2];
  const float* pw1 = (const float*)d_in[3];
  const float* pb1 = (const float*)d_in[4];
  const float* pw2 = (const float*)d_in[5];
  const float* pb2 = (const float*)d_in[6];
  const float* fw1 = (const float*)d_in[7];
  const float* fb1 = (const float*)d_in[8];
  const float* fw2 = (const float*)d_in[9];
  const float* fb2 = (const float*)d_in[10];
  float* out = (float*)d_out;
  float* ws  = (float*)d_ws;

  k_mlp<<<32, 384, 0, stream>>>(f, bf, pw1, pb1, pw2, pb2, fw1, fb1, fw2,
                                fb2, ws);
  dim3 grid(64, 8);
  k_render<<<grid, 256, 0, stream>>>(x, ws, out);
}

// Round 13
// 98.868 us; speedup vs baseline: 1.1317x; 1.0123x over previous
//
#include <hip/hip_runtime.h>

// Problem constants
#define HWSZ 65536             // 256*256
#define PLANE (3 * HWSZ)       // one batch's [3,H,W]
#define OUTSTRIDE (8 * PLANE)  // one full output tensor [8,3,256,256]
#define MAGIC 0x13572468       // != 0xAAAAAAAA ws poison

// ---------------------------------------------------------------------------
// Fused MLP: 32 blocks x 384 (R12 structure; phase-B weights prefetched
// before the flag spin so their fetch latency hides behind the wait).
__global__ __launch_bounds__(384) void k_mlp(
    const float* __restrict__ f, const float* __restrict__ bf,
    const float* __restrict__ pw1, const float* __restrict__ pb1,
    const float* __restrict__ pw2, const float* __restrict__ pb2,
    const float* __restrict__ fw1, const float* __restrict__ fb1,
    const float* __restrict__ fw2, const float* __restrict__ fb2,
    float* __restrict__ ws) {
  __shared__ float smem[2304];
  int t = threadIdx.x, blk = blockIdx.x;

  float* outs  = ws;          // [4,8,192]
  float* hc    = ws + 12288;  // [8,192]
  float* param = ws + 13824;  // [8,192]
  int* fbase = (int*)(ws + 16384);
  // flagA[i] = fbase[i*16] (i<32); flagB[i] = fbase[(64+i)*16]

  // ======== Phase A: proj for (k,b) ========
  int k = blk >> 3, b = blk & 7;
  {
    int q = t % 48, s = t / 48;  // s in 0..7
    float* sf  = smem;           // 512
    float* red = smem + 512;     // 8*192
    float* sh  = smem + 2048;    // 192

    const float* feat = ((k & 1) ? bf : f) + b * 512;
    for (int i = t; i < 512; i += 384) sf[i] = feat[i];
    __syncthreads();

    {  // 512 -> 192
      const float4* w = (const float4*)(pw1 + (size_t)k * (512 * 192));
      float4 acc = {0.f, 0.f, 0.f, 0.f};
      int i0 = s * 64;
      for (int r = 0; r < 4; ++r) {
        float4 wv[16];
#pragma unroll
        for (int j = 0; j < 16; ++j)
          wv[j] = w[(size_t)(i0 + r * 16 + j) * 48 + q];
#pragma unroll
        for (int j = 0; j < 16; ++j) {
          float v = sf[i0 + r * 16 + j];
          acc.x = fmaf(v, wv[j].x, acc.x); acc.y = fmaf(v, wv[j].y, acc.y);
          acc.z = fmaf(v, wv[j].z, acc.z); acc.w = fmaf(v, wv[j].w, acc.w);
        }
      }
      ((float4*)(red + s * 192))[q] = acc;
    }
    __syncthreads();
    if (t < 192) {
      float a = pb1[k * 192 + t];
#pragma unroll
      for (int s2 = 0; s2 < 8; ++s2) a += red[s2 * 192 + t];
      sh[t] = fmaxf(a, 0.f);
    }
    __syncthreads();
    {  // 192 -> 192
      const float4* w = (const float4*)(pw2 + (size_t)k * (192 * 192));
      float4 acc = {0.f, 0.f, 0.f, 0.f};
      int i0 = s * 24;
      for (int r = 0; r < 2; ++r) {
        float4 wv[12];
#pragma unroll
        for (int j = 0; j < 12; ++j)
          wv[j] = w[(size_t)(i0 + r * 12 + j) * 48 + q];
#pragma unroll
        for (int j = 0; j < 12; ++j) {
          float v = sh[i0 + r * 12 + j];
          acc.x = fmaf(v, wv[j].x, acc.x); acc.y = fmaf(v, wv[j].y, acc.y);
          acc.z = fmaf(v, wv[j].z, acc.z); acc.w = fmaf(v, wv[j].w, acc.w);
        }
      }
      ((float4*)(red + s * 192))[q] = acc;
    }
    __syncthreads();
    if (t < 192) {
      float a = pb2[k * 192 + t];
#pragma unroll
      for (int s2 = 0; s2 < 8; ++s2) a += red[s2 * 192 + t];
      outs[(k * 8 + b) * 192 + t] = a;
    }
    __syncthreads();  // drain stores before fence
    if (t == 0) {
      __threadfence();
      atomicExch(&fbase[blk * 16], MAGIC);
    }
  }

  // ======== Phase B1: fc1 for (b2 = blk&7, quarter c4 = blk>>3) ========
  int b2 = blk & 7, c4 = blk >> 3, ob2 = c4 * 48;
  int q = t % 12, s = t / 12;  // s in 0..31

  // prefetch fw1 slice (independent of outs) BEFORE the spin
  float4 wv1[18];
  {
    const float4* w = (const float4*)fw1;
    int i0 = s * 18;
#pragma unroll
    for (int j = 0; j < 18; ++j)
      wv1[j] = w[(size_t)(i0 + j) * 48 + (ob2 >> 2) + q];
  }

  if (t < 4) {
    while (atomicAdd(&fbase[(t * 8 + b2) * 16], 0) != MAGIC)
      __builtin_amdgcn_s_sleep(2);
  }
  __syncthreads();
  if (t == 0) __threadfence();  // acquire
  __syncthreads();

  {
    float* sc  = smem;           // 576
    float* red = smem + 576;     // 32*48
    for (int idx = t; idx < 576; idx += 384) {
      float v;
      if (idx < 192)      v = outs[(0 * 8 + b2) * 192 + idx];
      else if (idx < 384) v = outs[(1 * 8 + b2) * 192 + (idx - 192)];
      else                v = outs[(2 * 8 + b2) * 192 + (idx - 384)] +
                              outs[(3 * 8 + b2) * 192 + (idx - 384)];
      sc[idx] = v;
    }
    __syncthreads();
    float4 acc = {0.f, 0.f, 0.f, 0.f};
    int i0 = s * 18;
#pragma unroll
    for (int j = 0; j < 18; ++j) {
      float v = sc[i0 + j];
      acc.x = fmaf(v, wv1[j].x, acc.x); acc.y = fmaf(v, wv1[j].y, acc.y);
      acc.z = fmaf(v, wv1[j].z, acc.z); acc.w = fmaf(v, wv1[j].w, acc.w);
    }
    ((float4*)(red + s * 48))[q] = acc;
    __syncthreads();
    if (t < 48) {
      float a = fb1[ob2 + t];
#pragma unroll
      for (int s2 = 0; s2 < 32; ++s2) a += red[s2 * 48 + t];
      hc[b2 * 192 + ob2 + t] = fmaxf(a, 0.f);
    }
    __syncthreads();
    if (t == 0) {
      __threadfence();
      atomicExch(&fbase[(64 + blk) * 16], MAGIC);
    }
  }

  // ======== Phase B2: fc2, same (b2, c4) ========
  // prefetch fw2 slice before the spin
  float4 wv2[6];
  {
    const float4* w = (const float4*)fw2;
    int i0 = s * 6;
#pragma unroll
    for (int j = 0; j < 6; ++j)
      wv2[j] = w[(size_t)(i0 + j) * 48 + (ob2 >> 2) + q];
  }

  if (t < 4) {
    while (atomicAdd(&fbase[(64 + t * 8 + b2) * 16], 0) != MAGIC)
      __builtin_amdgcn_s_sleep(2);
  }
  __syncthreads();
  if (t == 0) __threadfence();  // acquire
  __syncthreads();

  {
    float* sh  = smem;           // 192
    float* red = smem + 576;     // 32*48
    if (t < 192) sh[t] = hc[b2 * 192 + t];
    __syncthreads();
    float4 acc = {0.f, 0.f, 0.f, 0.f};
    int i0 = s * 6;
#pragma unroll
    for (int j = 0; j < 6; ++j) {
      float v = sh[i0 + j];
      acc.x = fmaf(v, wv2[j].x, acc.x); acc.y = fmaf(v, wv2[j].y, acc.y);
      acc.z = fmaf(v, wv2[j].z, acc.z); acc.w = fmaf(v, wv2[j].w, acc.w);
    }
    ((float4*)(red + s * 48))[q] = acc;
    __syncthreads();
    if (t < 48) {
      float a = fb2[ob2 + t];
#pragma unroll
      for (int s2 = 0; s2 < 32; ++s2) a += red[s2 * 48 + t];
      param[b2 * 192 + ob2 + t] = a;
    }
  }
}

// ---------------------------------------------------------------------------
// Render: 256 blocks (32,8) x 256 threads, 2 float4 per thread per channel.
// LUT entry e[k] = {S_k*norm/64, p_k*norm}. Gray curves share k/tt.
__global__ __launch_bounds__(256) void k_render(
    const float* __restrict__ x, const float* __restrict__ ws,
    float* __restrict__ out) {
  int b = blockIdx.y, t = threadIdx.x;
  int wave = t >> 6, lane = t & 63;
  const float* outs  = ws;
  const float* param = ws + 13824;
  __shared__ float2 tab[576];

  // prefetch both x float4 groups
  int s4a = blockIdx.x * 512 + t, s4b = s4a + 256;
  const float* xb = x + (size_t)b * PLANE;
  float4 vr0 = ((const float4*)(xb))[s4a];
  float4 vr1 = ((const float4*)(xb))[s4b];
  float4 vg0 = ((const float4*)(xb + HWSZ))[s4a];
  float4 vg1 = ((const float4*)(xb + HWSZ))[s4b];
  float4 vb0 = ((const float4*)(xb + 2 * HWSZ))[s4a];
  float4 vb1 = ((const float4*)(xb + 2 * HWSZ))[s4b];

  for (int cur = wave; cur < 9; cur += 4) {
    int oi = cur / 3, c = cur - oi * 3;
    const float* src = (oi == 0) ? param + b * 192 + c * 64
                                 : outs + ((oi - 1) * 8 + b) * 192 + c * 64;
    float p = src[lane];
    float v = p;  // inclusive scan
#pragma unroll
    for (int d = 1; d < 64; d <<= 1) {
      float n = __shfl_up(v, d, 64);
      if (lane >= d) v += n;
    }
    float total = __shfl(v, 63, 64);
    float norm = 64.f / (total + 1e-30f);
    tab[cur * 64 + lane] = make_float2((v - p) * 0.015625f * norm, p * norm);
  }
  __syncthreads();

  auto idx_of = [&](float v, int& kk, float& tt) {
    int k = (int)(v * 64.f);
    k = k < 0 ? 0 : (k > 63 ? 63 : k);
    kk = k;
    tt = v - (float)k * 0.015625f;
  };
  auto evk = [&](int cur, int k, float tt) -> float {
    float2 e = tab[cur * 64 + k];
    return fmaf(tt, e.y, e.x);
  };
  auto ev4 = [&](int cur, float4 v) -> float4 {
    int k; float tt; float4 r;
    idx_of(v.x, k, tt); r.x = evk(cur, k, tt);
    idx_of(v.y, k, tt); r.y = evk(cur, k, tt);
    idx_of(v.z, k, tt); r.z = evk(cur, k, tt);
    idx_of(v.w, k, tt); r.w = evk(cur, k, tt);
    return r;
  };

  float* o0 = out + (size_t)b * PLANE;
  float* o1 = out + OUTSTRIDE + (size_t)b * PLANE;
  float* o2 = out + 2 * OUTSTRIDE + (size_t)b * PLANE;

  auto process = [&](int s4, float4 vr, float4 vg, float4 vb) {
    float4 gr;
    gr.x = fmaf(0.299f, vr.x, fmaf(0.587f, vg.x, 0.114f * vb.x));
    gr.y = fmaf(0.299f, vr.y, fmaf(0.587f, vg.y, 0.114f * vb.y));
    gr.z = fmaf(0.299f, vr.z, fmaf(0.587f, vg.z, 0.114f * vb.z));
    gr.w = fmaf(0.299f, vr.w, fmaf(0.587f, vg.w, 0.114f * vb.w));

    ((float4*)(o0))[s4]            = ev4(0, vr);
    ((float4*)(o0 + HWSZ))[s4]     = ev4(1, vg);
    ((float4*)(o0 + 2 * HWSZ))[s4] = ev4(2, vb);

    // gray: shared piece index across curves 3..8
    int kx, ky, kz, kw; float tx, ty, tz, tw;
    idx_of(gr.x, kx, tx); idx_of(gr.y, ky, ty);
    idx_of(gr.z, kz, tz); idx_of(gr.w, kw, tw);
#pragma unroll
    for (int c = 0; c < 3; ++c) {
      float4 r;
      r.x = evk(3 + c, kx, tx); r.y = evk(3 + c, ky, ty);
      r.z = evk(3 + c, kz, tz); r.w = evk(3 + c, kw, tw);
      ((float4*)(o1 + c * HWSZ))[s4] = r;
    }
#pragma unroll
    for (int c = 0; c < 3; ++c) {
      float4 r;
      r.x = evk(6 + c, kx, tx); r.y = evk(6 + c, ky, ty);
      r.z = evk(6 + c, kz, tz); r.w = evk(6 + c, kw, tw);
      ((float4*)(o2 + c * HWSZ))[s4] = r;
    }
  };

  process(s4a, vr0, vg0, vb0);
  process(s4b, vr1, vg1, vb1);
}

// ---------------------------------------------------------------------------
extern "C" void kernel_launch(void* const* d_in, const int* in_sizes, int n_in,
                              void* d_out, int out_size, void* d_ws, size_t ws_size,
                              hipStream_t stream) {
  const float* x   = (const float*)d_in[0];
  const float* f   = (const float*)d_in[1];
  const float* bf  = (const float*)d_in[2];
  const float* pw1 = (const float*)d_in[3];
  const float* pb1 = (const float*)d_in[4];
  const float* pw2 = (const float*)d_in[5];
  const float* pb2 = (const float*)d_in[6];
  const float* fw1 = (const float*)d_in[7];
  const float* fb1 = (const float*)d_in[8];
  const float* fw2 = (const float*)d_in[9];
  const float* fb2 = (const float*)d_in[10];
  float* out = (float*)d_out;
  float* ws  = (float*)d_ws;

  k_mlp<<<32, 384, 0, stream>>>(f, bf, pw1, pb1, pw2, pb2, fw1, fb1, fw2,
                                fb2, ws);
  dim3 grid(32, 8);
  k_render<<<grid, 256, 0, stream>>>(x, ws, out);
}